// Round 11
// baseline (117.766 us; speedup 1.0000x reference)
//
#include <hip/hip_runtime.h>

namespace {

constexpr int NS = 256;      // samples
constexpr int MP = 128;      // patches
constexpr int TSTEPS = 200;  // timesteps
constexpr int BLK = 256;     // 4 waves for setup; wave 0 runs the loop

__device__ __forceinline__ float4 ldg4(const float* p) {
  return *reinterpret_cast<const float4*>(p);
}
__device__ __forceinline__ float clamp01(float v) {
  return fminf(fmaxf(v, 0.0f), 1.0f);
}
// f32 += dot(f16x2, f16x2) — single VOP3P instruction
__device__ __forceinline__ float dot2(unsigned a, unsigned b, float c) {
  float d;
  asm("v_dot2_f32_f16 %0, %1, %2, %3" : "=v"(d) : "v"(a), "v"(b), "v"(c));
  return d;
}
// pack two f32 -> f16x2 (RTZ); builtin returns __fp16 ext_vector(2)
__device__ __forceinline__ unsigned pkrtz(float a, float b) {
  typedef __fp16 h2v __attribute__((ext_vector_type(2)));
  h2v r = __builtin_amdgcn_cvt_pkrtz(a, b);
  return __builtin_bit_cast(unsigned, r);
}
// Swizzled float4 index into Q staging (R5-proven).
__device__ __forceinline__ int qidx(int row, int c4) {
  return (row << 5) + (c4 ^ ((row >> 3) & 7));
}

__global__ __launch_bounds__(BLK, 1)
void sir_meta_kernel(const float* __restrict__ Rg,
                     const float* __restrict__ Tg,
                     const float* __restrict__ rho0g,
                     const float* __restrict__ betag,
                     float* __restrict__ outg)
{
  __shared__ __align__(16) float rs[MP];         // 1/rowsum
  __shared__ __align__(16) float sbin[MP];       // sqrt(beta/neff)
  __shared__ __align__(16) float scr[BLK];
  __shared__ __align__(16) unsigned xh[64];      // x as packed f16 pairs
  __shared__ __align__(16) float qlds[MP * MP];  // Q = R*diag(sbin), swizzled
  __shared__ __align__(16) unsigned gh[MP * 36]; // G rows, f16x2, stride 36 u32

  const int tid = threadIdx.x;
  const int n = blockIdx.x;
  const float* __restrict__ Rn = Rg + (size_t)n * MP * MP;

  // ---- S1: row sums -> rs = 1/rowsum ----
  {
    const int wave = tid >> 6;
    const int lane = tid & 63;
    const int half = lane >> 5;
    const int l32 = lane & 31;
    for (int it = 0; it < 16; ++it) {
      const int row = wave * 32 + it * 2 + half;
      float4 v = ldg4(Rn + row * MP + l32 * 4);
      float s = (v.x + v.y) + (v.z + v.w);
      s += __shfl_xor(s, 1);
      s += __shfl_xor(s, 2);
      s += __shfl_xor(s, 4);
      s += __shfl_xor(s, 8);
      s += __shfl_xor(s, 16);
      if (l32 == 0) rs[row] = 1.0f / s;
    }
  }
  __syncthreads();

  // ---- S2: neff[c] = sum_i Rraw[i][c]*rs[i] -> sbin = sqrt(beta/neff) ----
  {
    const int c = tid & 127;
    const int h = tid >> 7;
    float a = 0.0f;
    #pragma unroll 8
    for (int i = 0; i < 64; ++i) {
      const int ig = h * 64 + i;
      a = fmaf(Rn[ig * MP + c], rs[ig], a);
    }
    scr[tid] = a;
  }
  __syncthreads();
  if (tid < 128) sbin[tid] = sqrtf(betag[n] / (scr[tid] + scr[tid + 128]));
  __syncthreads();

  // ---- S3a: stage Q = Rraw * diag(sbin) into LDS, swizzled ----
  {
    float4* q4 = reinterpret_cast<float4*>(qlds);
    #pragma unroll
    for (int u = 0; u < 16; ++u) {
      const int fi = u * BLK + tid;
      const int r = fi >> 5, c4 = fi & 31;
      float4 rv = ldg4(Rn + fi * 4);
      float4 sv = *reinterpret_cast<const float4*>(&sbin[c4 * 4]);
      q4[qidx(r, c4)] =
          make_float4(rv.x * sv.x, rv.y * sv.y, rv.z * sv.z, rv.w * sv.w);
    }
  }
  __syncthreads();

  // ---- S3b: 4-wave 8x8-tile GEMM; scale; pack f16 -> gh ----
  {
    const int wv = tid >> 6;
    const int g = (tid >> 4) & 3;
    const int k = tid & 15;
    const int rbase = wv * 32 + g * 8;
    const int cbase = k * 8;
    float acc[64];
    #pragma unroll
    for (int i = 0; i < 64; ++i) acc[i] = 0.0f;
    {
      const float4* q4 = reinterpret_cast<const float4*>(qlds);
      for (int kk = 0; kk < 32; ++kk) {
        float4 qa[8], qb[8];
        #pragma unroll
        for (int r = 0; r < 8; ++r) qa[r] = q4[qidx(rbase + r, kk)];
        #pragma unroll
        for (int c = 0; c < 8; ++c) qb[c] = q4[qidx(cbase + c, kk)];
        #pragma unroll
        for (int r = 0; r < 8; ++r) {
          #pragma unroll
          for (int c = 0; c < 8; ++c) {
            float a = acc[r * 8 + c];
            a = fmaf(qa[r].x, qb[c].x, a);
            a = fmaf(qa[r].y, qb[c].y, a);
            a = fmaf(qa[r].z, qb[c].z, a);
            a = fmaf(qa[r].w, qb[c].w, a);
            acc[r * 8 + c] = a;
          }
        }
      }
    }
    {
      float rsc[8];
      #pragma unroll
      for (int c = 0; c < 8; ++c) rsc[c] = rs[cbase + c];
      #pragma unroll
      for (int r = 0; r < 8; ++r) {
        const float rr = rs[rbase + r];
        uint4 w;
        w.x = pkrtz(acc[r*8+0] * rr * rsc[0], acc[r*8+1] * rr * rsc[1]);
        w.y = pkrtz(acc[r*8+2] * rr * rsc[2], acc[r*8+3] * rr * rsc[3]);
        w.z = pkrtz(acc[r*8+4] * rr * rsc[4], acc[r*8+5] * rr * rsc[5]);
        w.w = pkrtz(acc[r*8+6] * rr * rsc[6], acc[r*8+7] * rr * rsc[7]);
        *reinterpret_cast<uint4*>(&gh[(rbase + r) * 36 + k * 4]) = w;
      }
    }
  }
  __syncthreads();

  // ---- waves 1..3 retire; wave 0 is fully self-sufficient (no barriers) ----
  if (tid >= 64) return;
  const int l = tid;

  // G rows 2l, 2l+1 as f16 pairs: 128 VGPRs
  unsigned gA[64], gB[64];
  {
    #pragma unroll
    for (int q = 0; q < 16; ++q) {
      uint4 va = *reinterpret_cast<const uint4*>(&gh[(2 * l) * 36 + 4 * q]);
      gA[4*q+0] = va.x; gA[4*q+1] = va.y; gA[4*q+2] = va.z; gA[4*q+3] = va.w;
      uint4 vb = *reinterpret_cast<const uint4*>(&gh[(2 * l + 1) * 36 + 4 * q]);
      gB[4*q+0] = vb.x; gB[4*q+1] = vb.y; gB[4*q+2] = vb.z; gB[4*q+3] = vb.w;
    }
  }

  const float* Tn = Tg + n * 9;
  const float T00 = Tn[0], T01 = Tn[1], T02 = Tn[2];
  const float T10 = Tn[3], T11 = Tn[4], T12 = Tn[5];
  const float T20 = Tn[6], T21 = Tn[7], T22 = Tn[8];

  const float* rp = rho0g + ((size_t)n * MP + 2 * l) * 3;
  float a0 = rp[0], a1 = rp[1], a2 = rp[2];   // row 2l
  float b0 = rp[3], b1 = rp[4], b2 = rp[5];   // row 2l+1

  xh[l] = pkrtz(a0, b0);
  asm volatile("s_waitcnt lgkmcnt(0)" ::: "memory");

  float4* outp = reinterpret_cast<float4*>(outg) + (size_t)n * TSTEPS * MP + 2 * l;

  for (int s = 0; s < TSTEPS; ++s) {
    // issue all 16 broadcast x-reads first (uniform address: conflict-free)
    uint4 xv[16];
    #pragma unroll
    for (int q = 0; q < 16; ++q)
      xv[q] = *reinterpret_cast<const uint4*>(&xh[4 * q]);

    // off-chain while reads are in flight: emit pre-update state
    const float SA = 1.0f - ((a0 + a1) + a2);
    const float SB = 1.0f - ((b0 + b1) + b2);
    outp[0] = make_float4(SA, a0, a1, a2);
    outp[1] = make_float4(SB, b0, b1, b2);
    outp += MP;

    // both full row-dots in-lane: 128 dot2, 8 independent chains
    float pA0 = 0.f, pA1 = 0.f, pA2 = 0.f, pA3 = 0.f;
    float pB0 = 0.f, pB1 = 0.f, pB2 = 0.f, pB3 = 0.f;
    #pragma unroll
    for (int q = 0; q < 16; ++q) {
      pA0 = dot2(gA[4*q+0], xv[q].x, pA0);
      pA1 = dot2(gA[4*q+1], xv[q].y, pA1);
      pA2 = dot2(gA[4*q+2], xv[q].z, pA2);
      pA3 = dot2(gA[4*q+3], xv[q].w, pA3);
      pB0 = dot2(gB[4*q+0], xv[q].x, pB0);
      pB1 = dot2(gB[4*q+1], xv[q].y, pB1);
      pB2 = dot2(gB[4*q+2], xv[q].z, pB2);
      pB3 = dot2(gB[4*q+3], xv[q].w, pB3);
    }
    const float uA = (pA0 + pA1) + (pA2 + pA3);
    const float uB = (pB0 + pB1) + (pB2 + pB3);

    // chain tail: n0 for both rows -> packed f16 x-write
    const float na0 = clamp01(fmaf(a0, T00, fmaf(a1, T10, fmaf(a2, T20, SA * uA))));
    const float nb0 = clamp01(fmaf(b0, T00, fmaf(b1, T10, fmaf(b2, T20, SB * uB))));
    xh[l] = pkrtz(na0, nb0);

    // off-chain: rest of the state update
    const float na1 = clamp01(fmaf(a0, T01, fmaf(a1, T11, a2 * T21)));
    const float na2 = clamp01(fmaf(a0, T02, fmaf(a1, T12, a2 * T22)));
    const float nb1 = clamp01(fmaf(b0, T01, fmaf(b1, T11, b2 * T21)));
    const float nb2 = clamp01(fmaf(b0, T02, fmaf(b1, T12, b2 * T22)));
    a0 = na0; a1 = na1; a2 = na2;
    b0 = nb0; b1 = nb1; b2 = nb2;

    // wave-local: ensure the write retires before next iteration's reads
    asm volatile("s_waitcnt lgkmcnt(0)" ::: "memory");
  }
}

} // namespace

extern "C" void kernel_launch(void* const* d_in, const int* in_sizes, int n_in,
                              void* d_out, int out_size, void* d_ws, size_t ws_size,
                              hipStream_t stream)
{
  const float* Rg    = (const float*)d_in[0];
  const float* Tg    = (const float*)d_in[1];
  const float* rho0g = (const float*)d_in[2];
  const float* betag = (const float*)d_in[3];
  float* outg = (float*)d_out;
  sir_meta_kernel<<<NS, BLK, 0, stream>>>(Rg, Tg, rho0g, betag, outg);
}

// Round 12
// 90.675 us; speedup vs baseline: 1.2988x; 1.2988x over previous
//
#include <hip/hip_runtime.h>

namespace {

constexpr int NS = 256;      // samples
constexpr int MP = 128;      // patches
constexpr int TSTEPS = 200;  // timesteps
constexpr int BLK = 512;     // 8 waves -> 2 waves/SIMD (R6-proven)

__device__ __forceinline__ float4 ldg4(const float* p) {
  return *reinterpret_cast<const float4*>(p);
}
__device__ __forceinline__ float clamp01(float v) {
  return fminf(fmaxf(v, 0.0f), 1.0f);
}
// LDS-visibility barrier that does NOT drain vmcnt (stores stay in flight).
__device__ __forceinline__ void step_barrier() {
  asm volatile("s_waitcnt lgkmcnt(0)" ::: "memory");
  __builtin_amdgcn_s_barrier();
  asm volatile("" ::: "memory");
}
// f32 += dot(f16x2, f16x2) — single VOP3P instruction (R11-verified)
__device__ __forceinline__ float dot2(unsigned a, unsigned b, float c) {
  float d;
  asm("v_dot2_f32_f16 %0, %1, %2, %3" : "=v"(d) : "v"(a), "v"(b), "v"(c));
  return d;
}
// pack two f32 -> f16x2 (RTZ)
__device__ __forceinline__ unsigned pkrtz(float a, float b) {
  typedef __fp16 h2v __attribute__((ext_vector_type(2)));
  h2v r = __builtin_amdgcn_cvt_pkrtz(a, b);
  return __builtin_bit_cast(unsigned, r);
}
// x + dpp(y) rotate-add (R6-proven reduce): 0x121/0x122/0x124/0x128 row_ror 1/2/4/8
template <int CTRL>
__device__ __forceinline__ float dpp_radd(float x) {
  int yi = __builtin_amdgcn_update_dpp(0, __float_as_int(x), CTRL, 0xF, 0xF, true);
  return x + __int_as_float(yi);
}
// fetch value from lane k^1 (quad_perm [1,0,3,2])
__device__ __forceinline__ float dpp_xor1(float x) {
  int yi = __builtin_amdgcn_update_dpp(0, __float_as_int(x), 0xB1, 0xF, 0xF, true);
  return __int_as_float(yi);
}
// Swizzled uint4 (b128 = 8 f16) index into f16 Q: 16 quads/row, XOR row-octet
__device__ __forceinline__ int qidx16(int row, int ch) {
  return (row << 4) + (ch ^ ((row >> 3) & 7));
}

__global__ __launch_bounds__(BLK, 2)
void sir_meta_kernel(const float* __restrict__ Rg,
                     const float* __restrict__ Tg,
                     const float* __restrict__ rho0g,
                     const float* __restrict__ betag,
                     float* __restrict__ outg)
{
  __shared__ __align__(16) float rs[MP];          // 1/rowsum (f32 exact)
  __shared__ __align__(16) float sbin[MP];        // sqrt(beta/neff) (f32 exact)
  __shared__ __align__(16) float scr[BLK];
  __shared__ __align__(16) unsigned xh[2][64];    // x as f16 pairs, dbuffered
  __shared__ __align__(16) uint4 q16[MP * 16];    // Q = R*diag(sbin) in f16 (32KB)

  const int tid = threadIdx.x;
  const int n = blockIdx.x;
  const float* __restrict__ Rn = Rg + (size_t)n * MP * MP;

  // ---- S1: row sums -> rs = 1/rowsum (f32, exact) ----
  {
    const int wave = tid >> 6;
    const int lane = tid & 63;
    const int half = lane >> 5;
    const int l32 = lane & 31;
    for (int it = 0; it < 8; ++it) {
      const int row = wave * 16 + it * 2 + half;
      float4 v = ldg4(Rn + row * MP + l32 * 4);
      float s = (v.x + v.y) + (v.z + v.w);
      s += __shfl_xor(s, 1);
      s += __shfl_xor(s, 2);
      s += __shfl_xor(s, 4);
      s += __shfl_xor(s, 8);
      s += __shfl_xor(s, 16);
      if (l32 == 0) rs[row] = 1.0f / s;
    }
  }
  __syncthreads();

  // ---- S2: neff[c] = sum_i Rraw[i][c]*rs[i] -> sbin = sqrt(beta/neff) ----
  {
    const int c = tid & 127;
    const int h = tid >> 7;
    float a = 0.0f;
    #pragma unroll 8
    for (int i = 0; i < 32; ++i) {
      const int ig = h * 32 + i;
      a = fmaf(Rn[ig * MP + c], rs[ig], a);
    }
    scr[tid] = a;
  }
  __syncthreads();
  if (tid < 128)
    sbin[tid] = sqrtf(betag[n] /
        (((scr[tid] + scr[tid + 128]) + (scr[tid + 256] + scr[tid + 384]))));
  __syncthreads();

  // ---- S3a: stage Q = Rraw * diag(sbin) as f16 pairs (32KB, swizzled) ----
  {
    #pragma unroll
    for (int u = 0; u < 4; ++u) {
      const int fi8 = u * BLK + tid;      // 8-float chunk index, 0..2047
      const int r = fi8 >> 4, c8 = fi8 & 15;
      float4 lo = ldg4(Rn + r * MP + c8 * 8);
      float4 hi = ldg4(Rn + r * MP + c8 * 8 + 4);
      float4 s0 = *reinterpret_cast<const float4*>(&sbin[c8 * 8]);
      float4 s1 = *reinterpret_cast<const float4*>(&sbin[c8 * 8 + 4]);
      uint4 w;
      w.x = pkrtz(lo.x * s0.x, lo.y * s0.y);
      w.y = pkrtz(lo.z * s0.z, lo.w * s0.w);
      w.z = pkrtz(hi.x * s1.x, hi.y * s1.y);
      w.w = pkrtz(hi.z * s1.z, hi.w * s1.w);
      q16[qidx16(r, c8)] = w;
    }
  }
  __syncthreads();

  // Tile mapping (R6): wave wv(0..7), group g(0..3), lane k(0..15).
  // Lane owns G rows [rbase..rbase+4) x cols [8k..8k+8).
  const int wv = tid >> 6;
  const int g = (tid >> 4) & 3;
  const int k = tid & 15;
  const int rbase = wv * 16 + g * 4;
  const int cbase = k * 8;

  // ---- S3b: f16 GEMM via dot2 (f32 accum): half the LDS reads of R6 ----
  float acc[4][8];
  #pragma unroll
  for (int r = 0; r < 4; ++r)
    #pragma unroll
    for (int c = 0; c < 8; ++c) acc[r][c] = 0.0f;
  {
    #pragma unroll 4
    for (int ch = 0; ch < 16; ++ch) {
      uint4 qa[4], qb[8];
      #pragma unroll
      for (int r = 0; r < 4; ++r) qa[r] = q16[qidx16(rbase + r, ch)];
      #pragma unroll
      for (int c = 0; c < 8; ++c) qb[c] = q16[qidx16(cbase + c, ch)];
      #pragma unroll
      for (int r = 0; r < 4; ++r) {
        #pragma unroll
        for (int c = 0; c < 8; ++c) {
          float a = acc[r][c];
          a = dot2(qa[r].x, qb[c].x, a);
          a = dot2(qa[r].y, qb[c].y, a);
          a = dot2(qa[r].z, qb[c].z, a);
          a = dot2(qa[r].w, qb[c].w, a);
          acc[r][c] = a;
        }
      }
    }
  }
  // scale G = diag(rs) Q Q^T diag(rs); pack to f16 pairs matching x layout
  unsigned ac16[4][4];
  {
    float rsc[8];
    #pragma unroll
    for (int c = 0; c < 8; ++c) rsc[c] = rs[cbase + c];
    #pragma unroll
    for (int r = 0; r < 4; ++r) {
      const float rr = rs[rbase + r];
      #pragma unroll
      for (int q = 0; q < 4; ++q)
        ac16[r][q] = pkrtz(acc[r][2 * q] * rr * rsc[2 * q],
                           acc[r][2 * q + 1] * rr * rsc[2 * q + 1]);
    }
  }

  // ---- S4: state init. Lane owns row j = rbase + (k&3). ----
  const int j = rbase + (k & 3);
  const bool writer = (k < 4);
  const float* Tn = Tg + n * 9;
  const float T00 = Tn[0], T01 = Tn[1], T02 = Tn[2];
  const float T10 = Tn[3], T11 = Tn[4], T12 = Tn[5];
  const float T20 = Tn[6], T21 = Tn[7], T22 = Tn[8];
  const float* rp0 = rho0g + ((size_t)n * MP + j) * 3;
  float r0 = rp0[0], r1 = rp0[1], r2 = rp0[2];
  if (tid < 64) {
    const float* xp = rho0g + ((size_t)n * MP + 2 * tid) * 3;
    xh[0][tid] = pkrtz(xp[0], xp[3]);
  }
  __syncthreads();

  float4* outp = reinterpret_cast<float4*>(outg) + (size_t)n * TSTEPS * MP + j;
  const bool xwriter = (k == 0) | (k == 2);
  const int xslot = (rbase >> 1) + (k >> 1);

  for (int s = 0; s < TSTEPS; ++s) {
    // emit pre-update state (coalesced 256B/wave, fire-and-forget)
    const float S = 1.0f - ((r0 + r1) + r2);
    if (writer) *outp = make_float4(S, r0, r1, r2);
    outp += MP;

    // x: ONE b128 per lane (4 f16-pairs = this lane's 8 columns)
    const uint4 xv = reinterpret_cast<const uint4*>(&xh[s & 1][0])[k];

    // 4x8 tile matvec via dot2
    float p0 = dot2(ac16[0][0], xv.x, 0.0f);
    p0 = dot2(ac16[0][1], xv.y, p0);
    p0 = dot2(ac16[0][2], xv.z, p0);
    p0 = dot2(ac16[0][3], xv.w, p0);
    float p1 = dot2(ac16[1][0], xv.x, 0.0f);
    p1 = dot2(ac16[1][1], xv.y, p1);
    p1 = dot2(ac16[1][2], xv.z, p1);
    p1 = dot2(ac16[1][3], xv.w, p1);
    float p2 = dot2(ac16[2][0], xv.x, 0.0f);
    p2 = dot2(ac16[2][1], xv.y, p2);
    p2 = dot2(ac16[2][2], xv.z, p2);
    p2 = dot2(ac16[2][3], xv.w, p2);
    float p3 = dot2(ac16[3][0], xv.x, 0.0f);
    p3 = dot2(ac16[3][1], xv.y, p3);
    p3 = dot2(ac16[3][2], xv.z, p3);
    p3 = dot2(ac16[3][3], xv.w, p3);

    // 16-lane rotate-add reduce (R6-proven) + static select
    p0 = dpp_radd<0x121>(p0); p0 = dpp_radd<0x122>(p0);
    p0 = dpp_radd<0x124>(p0); p0 = dpp_radd<0x128>(p0);
    p1 = dpp_radd<0x121>(p1); p1 = dpp_radd<0x122>(p1);
    p1 = dpp_radd<0x124>(p1); p1 = dpp_radd<0x128>(p1);
    p2 = dpp_radd<0x121>(p2); p2 = dpp_radd<0x122>(p2);
    p2 = dpp_radd<0x124>(p2); p2 = dpp_radd<0x128>(p2);
    p3 = dpp_radd<0x121>(p3); p3 = dpp_radd<0x122>(p3);
    p3 = dpp_radd<0x124>(p3); p3 = dpp_radd<0x128>(p3);
    const float t0 = (k & 1) ? p1 : p0;
    const float t1 = (k & 1) ? p3 : p2;
    const float u = (k & 2) ? t1 : t0;

    // state update + clip
    const float ni = S * u;
    const float n0 = clamp01(fmaf(r0, T00, fmaf(r1, T10, fmaf(r2, T20, ni))));
    const float n1 = clamp01(fmaf(r0, T01, fmaf(r1, T11, r2 * T21)));
    const float n2 = clamp01(fmaf(r0, T02, fmaf(r1, T12, r2 * T22)));

    // pack adjacent-row n0 pair via DPP, single u32 write from lanes 0,2
    const float nb = dpp_xor1(n0);
    if (xwriter) xh[(s & 1) ^ 1][xslot] = pkrtz(n0, nb);

    r0 = n0; r1 = n1; r2 = n2;

    // LDS-only barrier: x writes visible; global stores stay in flight
    step_barrier();
  }
}

} // namespace

extern "C" void kernel_launch(void* const* d_in, const int* in_sizes, int n_in,
                              void* d_out, int out_size, void* d_ws, size_t ws_size,
                              hipStream_t stream)
{
  const float* Rg    = (const float*)d_in[0];
  const float* Tg    = (const float*)d_in[1];
  const float* rho0g = (const float*)d_in[2];
  const float* betag = (const float*)d_in[3];
  float* outg = (float*)d_out;
  sir_meta_kernel<<<NS, BLK, 0, stream>>>(Rg, Tg, rho0g, betag, outg);
}